// Round 2
// baseline (352.053 us; speedup 1.0000x reference)
//
#include <hip/hip_runtime.h>
#include <hip/hip_bf16.h>

#define NTOK    32768
#define DIMD    1024
#define RNK     128
#define NEXP    7
#define FULLKEY 7
#define TGX     96      // token-tile grid width (grid-stride covers any distribution)

using f32x4 = __attribute__((ext_vector_type(4))) float;
using s16x8 = __attribute__((ext_vector_type(8))) short;

__device__ __forceinline__ unsigned short f2bf(float f) {
    unsigned u = __float_as_uint(f);
    u += 0x7fffu + ((u >> 16) & 1u);   // RNE; inputs have no NaN
    return (unsigned short)(u >> 16);
}

__device__ __forceinline__ unsigned lra_bits(const int* __restrict__ mask) {
    unsigned bits = 0u;
#pragma unroll
    for (int i = 0; i < NEXP; ++i) {
        int m = mask[i];
        m = m < 0 ? 0 : (m > 7 ? 7 : m);
        bits |= (1u << m);
    }
    return bits;
}

// ---- merged prep: convert weights | bucket tokens | copy inactive rows ----
__global__ void prep_kernel(const float* __restrict__ x, const int* __restrict__ ridx,
                            const int* __restrict__ mask,
                            const float* __restrict__ Wd, const float* __restrict__ Wu,
                            unsigned short* __restrict__ WdB, unsigned short* __restrict__ WuB,
                            int* __restrict__ counts, int* __restrict__ bucket,
                            float* __restrict__ out) {
    const int b = blockIdx.x;
    const int tid = threadIdx.x;
    if (b < 1792) {
        // convert Wd+Wu f32 -> bf16 (4 elems/thread)
        const int NE = NEXP * RNK * DIMD;              // 917504
        int i = (b * 256 + tid) * 4;
        const float* src; unsigned short* dst; int off;
        if (i < NE) { src = Wd; dst = WdB; off = i; }
        else        { src = Wu; dst = WuB; off = i - NE; }
        if (off < NE) {
            float4 v = *reinterpret_cast<const float4*>(src + off);
            ushort4 o;
            o.x = f2bf(v.x); o.y = f2bf(v.y); o.z = f2bf(v.z); o.w = f2bf(v.w);
            *reinterpret_cast<ushort4*>(dst + off) = o;
        }
    } else if (b < 1920) {
        // bucket tokens by expert
        int t = (b - 1792) * 256 + tid;
        if (t < NTOK) {
            unsigned bits = lra_bits(mask);
            int k = ridx[t];
            if (k != FULLKEY && ((bits >> k) & 1u)) {
                int p = atomicAdd(&counts[k], 1);
                bucket[k * NTOK + p] = t;
            }
        }
    } else {
        // out = x for inactive tokens
        unsigned bits = lra_bits(mask);
        for (int t = b - 1920; t < NTOK; t += 2048) {
            int k = ridx[t];
            bool act = (k != FULLKEY) && ((bits >> k) & 1u);
            if (!act) {
                const float4* src = reinterpret_cast<const float4*>(x + (size_t)t * DIMD);
                float4* dst = reinterpret_cast<float4*>(out + (size_t)t * DIMD);
                dst[tid] = src[tid];
            }
        }
    }
}

// ---- down = bf16(X) * Wd^T  -> downB[token][128] bf16 (row-major) ----
// One wave per 16 tokens. No barriers: B-frags direct from L2-resident WdB,
// A-frags direct from x (f32->bf16), per-wave LDS only for C->row-major transpose.
__launch_bounds__(256)
__global__ void down_kernel(const float* __restrict__ x,
                            const unsigned short* __restrict__ WdB,
                            const int* __restrict__ counts,
                            const int* __restrict__ bucket,
                            unsigned short* __restrict__ downB) {
    const int e = blockIdx.y;
    const int n = counts[e];
    const int tid = threadIdx.x;
    const int w = tid >> 6, l = tid & 63, l15 = l & 15, lk = l >> 4;

    __shared__ unsigned short sT[4 * 2048];   // 4KB per wave
    unsigned short* myT = sT + w * 2048;
    char* myTb = reinterpret_cast<char*>(myT);

    const f32x4 zero = {0.f, 0.f, 0.f, 0.f};

    for (int base = blockIdx.x * 64; base < n; base += TGX * 64) {
        int idx = base + 16 * w + l15;
        if (idx >= n) idx = n - 1;
        const int t = bucket[e * NTOK + idx];
        const float* xr = x + (size_t)t * DIMD;

        f32x4 acc[8];
#pragma unroll
        for (int i = 0; i < 8; ++i) acc[i] = zero;

        for (int kc = 0; kc < 8; ++kc) {
            s16x8 a[4];
#pragma unroll
            for (int ks = 0; ks < 4; ++ks) {
                const float* p = xr + kc * 128 + ks * 32 + lk * 8;
                const f32x4 v0 = *reinterpret_cast<const f32x4*>(p);
                const f32x4 v1 = *reinterpret_cast<const f32x4*>(p + 4);
                s16x8 av;
#pragma unroll
                for (int j = 0; j < 4; ++j) {
                    av[j]     = (short)f2bf(v0[j]);
                    av[4 + j] = (short)f2bf(v1[j]);
                }
                a[ks] = av;
            }
#pragma unroll
            for (int ks = 0; ks < 4; ++ks) {
#pragma unroll
                for (int nn = 0; nn < 8; ++nn) {
                    const s16x8 bfr = *reinterpret_cast<const s16x8*>(
                        WdB + ((size_t)(e * RNK + 16 * nn + l15)) * DIMD + kc * 128 + ks * 32 + lk * 8);
                    acc[nn] = __builtin_amdgcn_mfma_f32_16x16x32_bf16(a[ks], bfr, acc[nn], 0, 0, 0);
                }
            }
        }

        // C layout (col=l&15 -> rank, row=(l>>4)*4+j -> token) -> LDS [tok][rank] bf16, swizzled
#pragma unroll
        for (int nn = 0; nn < 8; ++nn) {
#pragma unroll
            for (int j = 0; j < 4; ++j) {
                const int tokl = lk * 4 + j;
                const int byt = (tokl * 256 + (16 * nn + l15) * 2) ^ ((tokl & 7) << 4);
                myT[byt >> 1] = f2bf(acc[nn][j]);
            }
        }
        // copy LDS (de-swizzled) -> downB row-major
#pragma unroll
        for (int it = 0; it < 4; ++it) {
            const int row = l >> 2;
            const int colb = (l & 3) * 16 + it * 64;
            const int byt = (row * 256 + colb) ^ ((row & 7) << 4);
            const s16x8 v = *reinterpret_cast<const s16x8*>(myTb + byt);
            const int trow = __shfl(t, row);
            *reinterpret_cast<s16x8*>(downB + (size_t)trow * RNK + (colb >> 1)) = v;
        }
    }
}

// ---- up chunk: out[t][dc*128..] = x + down[t]*Wu^T  (one 128-dim chunk/block) ----
__launch_bounds__(256)
__global__ void up_kernel(const float* __restrict__ x,
                          const unsigned short* __restrict__ WuB,
                          const unsigned short* __restrict__ downB,
                          const int* __restrict__ counts,
                          const int* __restrict__ bucket,
                          float* __restrict__ out) {
    const int e = blockIdx.y;
    const int dc = blockIdx.z;
    const int n = counts[e];
    const int tid = threadIdx.x;
    const int w = tid >> 6, l = tid & 63, l15 = l & 15, lk = l >> 4;
    const f32x4 zero = {0.f, 0.f, 0.f, 0.f};

    for (int base = blockIdx.x * 64; base < n; base += TGX * 64) {
        int idx = base + 16 * w + l15;
        if (idx >= n) idx = n - 1;
        const int t = bucket[e * NTOK + idx];

        s16x8 a2[4];
#pragma unroll
        for (int ks = 0; ks < 4; ++ks)
            a2[ks] = *reinterpret_cast<const s16x8*>(downB + (size_t)t * RNK + ks * 32 + lk * 8);

        int t4[4];
#pragma unroll
        for (int j = 0; j < 4; ++j) t4[j] = __shfl(t, lk * 4 + j);

        f32x4 acc[8];
#pragma unroll
        for (int i = 0; i < 8; ++i) acc[i] = zero;

#pragma unroll
        for (int ks = 0; ks < 4; ++ks) {
#pragma unroll
            for (int nn = 0; nn < 8; ++nn) {
                const s16x8 bfr = *reinterpret_cast<const s16x8*>(
                    WuB + ((size_t)(e * DIMD + dc * 128 + 16 * nn + l15)) * RNK + ks * 32 + lk * 8);
                acc[nn] = __builtin_amdgcn_mfma_f32_16x16x32_bf16(a2[ks], bfr, acc[nn], 0, 0, 0);
            }
        }

#pragma unroll
        for (int nn = 0; nn < 8; ++nn) {
#pragma unroll
            for (int j = 0; j < 4; ++j) {
                const size_t off = (size_t)t4[j] * DIMD + dc * 128 + 16 * nn + l15;
                out[off] = x[off] + acc[nn][j];
            }
        }
    }
}

extern "C" void kernel_launch(void* const* d_in, const int* in_sizes, int n_in,
                              void* d_out, int out_size, void* d_ws, size_t ws_size,
                              hipStream_t stream) {
    const float* x  = (const float*)d_in[0];
    const int* ridx = (const int*)d_in[1];
    const int* mask = (const int*)d_in[2];
    const float* Wd = (const float*)d_in[3];
    const float* Wu = (const float*)d_in[4];
    float* out = (float*)d_out;

    char* ws = (char*)d_ws;
    int* counts = (int*)ws;                                    // 256 B
    int* bucket = (int*)(ws + 256);                            // 917504 B
    unsigned short* WdB   = (unsigned short*)(ws + 917760);    // 1835008 B
    unsigned short* WuB   = (unsigned short*)(ws + 2752768);   // 1835008 B
    unsigned short* downB = (unsigned short*)(ws + 4587776);   // 8388608 B (tot ~12.97 MB)

    hipMemsetAsync(counts, 0, 8 * sizeof(int), stream);
    prep_kernel<<<dim3(3968), dim3(256), 0, stream>>>(x, ridx, mask, Wd, Wu, WdB, WuB, counts, bucket, out);
    down_kernel<<<dim3(TGX, NEXP), dim3(256), 0, stream>>>(x, WdB, counts, bucket, downB);
    up_kernel<<<dim3(TGX, NEXP, 8), dim3(256), 0, stream>>>(x, WuB, downB, counts, bucket, out);
}